// Round 16
// baseline (46.984 us; speedup 1.0000x reference)
//
#include <hip/hip_runtime.h>

static constexpr float ALPHA = 0.1f;

typedef _Float16 h2 __attribute__((ext_vector_type(2)));

#define TW 64
#define TH 12
// hist window: rows h0-4 .. h0+15 (20 rows), cols w0-8 .. w0+75 (84 cols)
// jitter: |dx| < 4.8 px, |dy| < 2.7 px -> taps within [w-6,w+6] x [h-4,h+4]
// LDS layout: f16 RGBA-interleaved — texel = uint2{(R,G),(B,pad)} (8 B).
// One ds_read_b64 per tap fetches all 3 channels.
#define HROWS 20
#define HCOLS 84
#define NTEX (HROWS * HCOLS)     // 1680 texels * 8 B = 13440 B LDS

__device__ __forceinline__ int iclamp(int v, int lo, int hi) { return min(max(v, lo), hi); }

__device__ __forceinline__ unsigned pk(float a, float b) {
    return __builtin_bit_cast(unsigned, __builtin_amdgcn_cvt_pkrtz(a, b));
}
__device__ __forceinline__ h2 toh2(unsigned u) { return __builtin_bit_cast(h2, u); }
__device__ __forceinline__ h2 bc2(float v) { return toh2(pk(v, v)); }

struct Setup {
    int mA, m1, mB;       // global tap coords (unclamped); m2 = m1+1
    float t, w0, w3, w12;
};

__device__ __forceinline__ Setup axis_setup(float gcoord, float S) {
    Setup s;
    float pos = (gcoord + 1.0f) * 0.5f * S;
    float pm  = floorf(pos - 0.5f);
    float f   = pos - (pm + 0.5f);
    float f2 = f * f, f3 = f2 * f;
    s.w0  = -0.5f * f3 + f2 - 0.5f * f;
    float w2 = -1.5f * f3 + 2.0f * f2 + 0.5f * f;
    s.w3  =  0.5f * f3 - 0.5f * f2;
    s.w12 = (1.5f * f3 - 2.5f * f2 + 1.0f) + w2;
    float p12 = pm + __fdividef(w2, s.w12);
    float fl  = floorf(p12);
    s.t = p12 - fl;
    s.m1 = (int)fl;
    int m = (int)pm;
    s.mA = m - 1; s.mB = m + 2;
    return s;
}

__global__ __launch_bounds__(256, 4) void taa_kernel(
    const float* __restrict__ x, const float* __restrict__ mv,
    const float* __restrict__ hist, float* __restrict__ out)
{
    constexpr int N = 2, H = 1080, W = 1920, HW = H * W;
    constexpr int NTX = W / TW;          // 30
    constexpr int NTY = H / TH;          // 90
    constexpr int NWG = N * NTX * NTY;   // 5400 (%8 == 0)
    constexpr int Q = NWG / 8;

    __shared__ __align__(8) uint2 Lh[NTEX];

    // Bijective XCD swizzle (NWG%8==0): vertically adjacent tiles share an XCD L2.
    int d = blockIdx.x;
    int work = (d & 7) * Q + (d >> 3);
    int n   = work / (NTX * NTY);
    int rem = work - n * (NTX * NTY);
    int ty  = rem / NTX;
    int tx  = rem - ty * NTX;
    const int w0 = tx * TW, h0 = ty * TH;

    const int lx = threadIdx.x & 63;
    const int wv = threadIdx.x >> 6;      // 0..3; thread owns rows 3wv..3wv+2
    const int wpix = w0 + lx;
    const int hbase = h0 + 3 * wv;

    const float* hn = hist + n * 3 * HW;
    const float* xn = x    + n * 3 * HW;

    // ---- mv loads (coalesced float2, issue first) ----
    const float2 g0 = ((const float2*)mv)[n * HW + hbase * W + wpix];
    const float2 g1 = ((const float2*)mv)[n * HW + (hbase + 1) * W + wpix];
    const float2 g2 = ((const float2*)mv)[n * HW + (hbase + 2) * W + wpix];

    // ---- stage history window into LDS, f16 RGBA-interleaved ----
    const bool interior = (tx >= 1) && (tx <= NTX - 2) &&
                          (h0 >= 4) && (h0 + TH + 3 <= H - 1);
    if (interior) {
        for (int idx = threadIdx.x; idx < NTEX; idx += 256) {
            int r  = idx / HCOLS;
            int cc = idx - r * HCOLS;
            const float* src = hn + (h0 - 4 + r) * W + (w0 - 8) + cc;
            Lh[idx] = make_uint2(pk(src[0], src[HW]), pk(src[2 * HW], 0.0f));
        }
    } else {
        for (int idx = threadIdx.x; idx < NTEX; idx += 256) {
            int r  = idx / HCOLS;
            int cc = idx - r * HCOLS;
            int gr = iclamp(h0 - 4 + r, 0, H - 1);
            int gc = iclamp(w0 - 8 + cc, 0, W - 1);
            const float* src = hn + gr * W + gc;
            Lh[idx] = make_uint2(pk(src[0], src[HW]), pk(src[2 * HW], 0.0f));
        }
    }

    // ---- x neighborhood (coalesced VMEM; overlaps staging latency) ----
    // rows hbase-1 .. hbase+3 (5 rows shared by the thread's 3 pixels)
    int rg0 = iclamp(hbase - 1, 0, H - 1) * W;
    int rg1 = hbase * W;
    int rg2 = (hbase + 1) * W;
    int rg3 = (hbase + 2) * W;
    int rg4 = iclamp(hbase + 3, 0, H - 1) * W;
    const int rg[5] = {rg0, rg1, rg2, rg3, rg4};

    float hmx[3][5], hmn[3][5], xmid[3][3];
    if (tx >= 1 && tx <= NTX - 2) {
#pragma unroll
        for (int c = 0; c < 3; ++c) {
            const float* xc = xn + c * HW + wpix;
#pragma unroll
            for (int rr = 0; rr < 5; ++rr) {
                const float* p = xc + rg[rr];
                float a = p[-1], b = p[0], e = p[1];
                hmx[c][rr]  = fmaxf(fmaxf(a, b), e);
                hmn[c][rr]  = fminf(fminf(a, b), e);
                if (rr >= 1 && rr <= 3) xmid[c][rr - 1] = b;
            }
        }
    } else {
        const int wm = max(wpix - 1, 0), wp = min(wpix + 1, W - 1);
#pragma unroll
        for (int c = 0; c < 3; ++c) {
            const float* xc = xn + c * HW;
#pragma unroll
            for (int rr = 0; rr < 5; ++rr) {
                float a = xc[rg[rr] + wm];
                float b = xc[rg[rr] + wpix];
                float e = xc[rg[rr] + wp];
                hmx[c][rr]  = fmaxf(fmaxf(a, b), e);
                hmn[c][rr]  = fminf(fminf(a, b), e);
                if (rr >= 1 && rr <= 3) xmid[c][rr - 1] = b;
            }
        }
    }

    // ---- bicubic setup for the 3 pixels (overlaps staging latency) ----
    Setup sx0 = axis_setup(g0.x, (float)W);
    Setup sy0 = axis_setup(g0.y, (float)H);
    Setup sx1 = axis_setup(g1.x, (float)W);
    Setup sy1 = axis_setup(g1.y, (float)H);
    Setup sx2 = axis_setup(g2.x, (float)W);
    Setup sy2 = axis_setup(g2.y, (float)H);

    __syncthreads();

    float* on = out + n * 3 * HW;

#pragma unroll
    for (int p = 0; p < 3; ++p) {
        const Setup& sx = (p == 0) ? sx0 : (p == 1) ? sx1 : sx2;
        const Setup& sy = (p == 0) ? sy0 : (p == 1) ? sy1 : sy2;

        const int lrA = iclamp(sy.mA     - (h0 - 4), 0, HROWS - 1);
        const int lr1 = iclamp(sy.m1     - (h0 - 4), 0, HROWS - 1);
        const int lr2 = iclamp(sy.m1 + 1 - (h0 - 4), 0, HROWS - 1);
        const int lrB = iclamp(sy.mB     - (h0 - 4), 0, HROWS - 1);
        const int lcA = iclamp(sx.mA     - (w0 - 8), 0, HCOLS - 1);
        const int lc1 = iclamp(sx.m1     - (w0 - 8), 0, HCOLS - 1);
        const int lc2 = iclamp(sx.m1 + 1 - (w0 - 8), 0, HCOLS - 1);
        const int lcB = iclamp(sx.mB     - (w0 - 8), 0, HCOLS - 1);

        const int rA = lrA * HCOLS, r1 = lr1 * HCOLS, r2 = lr2 * HCOLS, rB = lrB * HCOLS;

        // 12 b64 tap reads — each carries all 3 channels (f16)
        uint2 tA1 = Lh[rA + lc1], tA2 = Lh[rA + lc2];        // s1 pair
        uint2 tB1 = Lh[rB + lc1], tB2 = Lh[rB + lc2];        // s4 pair
        uint2 tL1 = Lh[r1 + lcA], tL2 = Lh[r2 + lcA];        // s2 pair
        uint2 tR1 = Lh[r1 + lcB], tR2 = Lh[r2 + lcB];        // s3 pair
        uint2 tC11 = Lh[r1 + lc1], tC12 = Lh[r1 + lc2];      // s5 quad
        uint2 tC21 = Lh[r2 + lc1], tC22 = Lh[r2 + lc2];

        const float tx_ = sx.t, ty_ = sy.t;
        const float omtx = 1.0f - tx_, omty = 1.0f - ty_;
        const float ww1 = sx.w12 * sy.w0;
        const float ww2 = sx.w0  * sy.w12;
        const float ww3 = sx.w3  * sy.w12;
        const float ww4 = sx.w12 * sy.w3;
        const float ww5 = sx.w12 * sy.w12;
        const float rrec = __fdividef(1.0f, ww1 + ww2 + ww3 + ww4 + ww5);

        // broadcast weights to packed f16
        const h2 htx = bc2(tx_),  homtx = bc2(omtx);
        const h2 hty = bc2(ty_),  homty = bc2(omty);
        const h2 hw1 = bc2(ww1), hw2 = bc2(ww2), hw3 = bc2(ww3),
                 hw4 = bc2(ww4), hw5 = bc2(ww5);

        // packed-f16 combine: .x=(R,G), .y=(B,pad)
        h2 A1rg = toh2(tA1.x), A1bp = toh2(tA1.y), A2rg = toh2(tA2.x), A2bp = toh2(tA2.y);
        h2 B1rg = toh2(tB1.x), B1bp = toh2(tB1.y), B2rg = toh2(tB2.x), B2bp = toh2(tB2.y);
        h2 L1rg = toh2(tL1.x), L1bp = toh2(tL1.y), L2rg = toh2(tL2.x), L2bp = toh2(tL2.y);
        h2 R1rg = toh2(tR1.x), R1bp = toh2(tR1.y), R2rg = toh2(tR2.x), R2bp = toh2(tR2.y);
        h2 C11rg = toh2(tC11.x), C11bp = toh2(tC11.y), C12rg = toh2(tC12.x), C12bp = toh2(tC12.y);
        h2 C21rg = toh2(tC21.x), C21bp = toh2(tC21.y), C22rg = toh2(tC22.x), C22bp = toh2(tC22.y);

        h2 s1rg = A1rg * homtx + A2rg * htx,  s1bp = A1bp * homtx + A2bp * htx;
        h2 s4rg = B1rg * homtx + B2rg * htx,  s4bp = B1bp * homtx + B2bp * htx;
        h2 s2rg = L1rg * homty + L2rg * hty,  s2bp = L1bp * homty + L2bp * hty;
        h2 s3rg = R1rg * homty + R2rg * hty,  s3bp = R1bp * homty + R2bp * hty;
        h2 s5rg = (C11rg * homtx + C12rg * htx) * homty + (C21rg * homtx + C22rg * htx) * hty;
        h2 s5bp = (C11bp * homtx + C12bp * htx) * homty + (C21bp * homtx + C22bp * htx) * hty;

        h2 accrg = s1rg * hw1 + s2rg * hw2 + s3rg * hw3 + s4rg * hw4 + s5rg * hw5;
        h2 accbp = s1bp * hw1 + s2bp * hw2 + s3bp * hw3 + s4bp * hw4 + s5bp * hw5;

        float rv[3] = { (float)accrg[0] * rrec, (float)accrg[1] * rrec, (float)accbp[0] * rrec };

        const int gpix = (hbase + p) * W + wpix;
#pragma unroll
        for (int c = 0; c < 3; ++c) {
            float mxv = fmaxf(fmaxf(hmx[c][p], hmx[c][p + 1]), hmx[c][p + 2]);
            float mnv = fminf(fminf(hmn[c][p], hmn[c][p + 1]), hmn[c][p + 2]);
            float reproj = fminf(fmaxf(rv[c], mnv), mxv);
            on[c * HW + gpix] = ALPHA * xmid[c][p] + (1.0f - ALPHA) * reproj;
        }
    }
}

extern "C" void kernel_launch(void* const* d_in, const int* in_sizes, int n_in,
                              void* d_out, int out_size, void* d_ws, size_t ws_size,
                              hipStream_t stream) {
    const float* x    = (const float*)d_in[0];
    const float* mv   = (const float*)d_in[1];
    const float* hist = (const float*)d_in[2];
    float* out = (float*)d_out;

    constexpr int NWG = 2 * (1920 / TW) * (1080 / TH);  // 5400
    taa_kernel<<<dim3(NWG, 1, 1), dim3(256, 1, 1), 0, stream>>>(x, mv, hist, out);
}

// Round 17
// 43.781 us; speedup vs baseline: 1.0732x; 1.0732x over previous
//
#include <hip/hip_runtime.h>

static constexpr float ALPHA = 0.1f;

typedef _Float16 h2 __attribute__((ext_vector_type(2)));

#define TW 64
#define TH 8
// hist window: rows h0-4 .. h0+11 (16 rows), cols w0-8 .. w0+75 (84 cols)
// jitter: |dx| < 4.8 px, |dy| < 2.7 px -> taps within [w-6,w+6] x [h-4,h+4]
// LDS layout: f16 RGBA-interleaved — texel = uint2{(R,G),(B,pad)} (8 B).
// One ds_read_b64 per tap fetches all 3 channels.
// CHAMPION (R14, 43.8 us): TH=8/256thr natural occupancy point; do not force
// launch_bounds above 4 (spills), do not widen tile (TLP loss), do not split
// channels (3x LDS instrs), do not change stride (conflicts are gather-intrinsic).
#define HROWS 16
#define HCOLS 84
#define NTEX (HROWS * HCOLS)     // 1344 texels * 8 B = 10752 B LDS

__device__ __forceinline__ int iclamp(int v, int lo, int hi) { return min(max(v, lo), hi); }

__device__ __forceinline__ unsigned pk(float a, float b) {
    return __builtin_bit_cast(unsigned, __builtin_amdgcn_cvt_pkrtz(a, b));
}
__device__ __forceinline__ h2 toh2(unsigned u) { return __builtin_bit_cast(h2, u); }
__device__ __forceinline__ h2 bc2(float v) { return toh2(pk(v, v)); }

struct Setup {
    int mA, m1, m2, mB;   // global tap coords (unclamped)
    float t, w0, w3, w12;
};

__device__ __forceinline__ Setup axis_setup(float gcoord, float S) {
    Setup s;
    float pos = (gcoord + 1.0f) * 0.5f * S;
    float pm  = floorf(pos - 0.5f);
    float f   = pos - (pm + 0.5f);
    float f2 = f * f, f3 = f2 * f;
    s.w0  = -0.5f * f3 + f2 - 0.5f * f;
    float w2 = -1.5f * f3 + 2.0f * f2 + 0.5f * f;
    s.w3  =  0.5f * f3 - 0.5f * f2;
    s.w12 = (1.5f * f3 - 2.5f * f2 + 1.0f) + w2;
    float p12 = pm + __fdividef(w2, s.w12);
    float fl  = floorf(p12);
    s.t = p12 - fl;
    int m = (int)pm, i12 = (int)fl;
    s.mA = m - 1; s.m1 = i12; s.m2 = i12 + 1; s.mB = m + 2;
    return s;
}

__global__ __launch_bounds__(256, 4) void taa_kernel(
    const float* __restrict__ x, const float* __restrict__ mv,
    const float* __restrict__ hist, float* __restrict__ out)
{
    constexpr int N = 2, H = 1080, W = 1920, HW = H * W;
    constexpr int NTX = W / TW;          // 30
    constexpr int NTY = H / TH;          // 135
    constexpr int NWG = N * NTX * NTY;   // 8100
    constexpr int Q = NWG / 8, R = NWG % 8;

    __shared__ __align__(8) uint2 Lh[NTEX];

    // Bijective XCD swizzle: each XCD owns a contiguous band of x-major work
    // ids -> vertically adjacent tiles share an XCD's L2 (FETCH 231->65 MB).
    int d = blockIdx.x;
    int xcd = d & 7, di = d >> 3;
    int work = (xcd < R ? xcd * (Q + 1) : R * (Q + 1) + (xcd - R) * Q) + di;
    int n   = work / (NTX * NTY);
    int rem = work - n * (NTX * NTY);
    int ty  = rem / NTX;
    int tx  = rem - ty * NTX;
    const int w0 = tx * TW, h0 = ty * TH;

    const int lx = threadIdx.x & 63;
    const int wv = threadIdx.x >> 6;      // 0..3; thread owns rows 2wv, 2wv+1
    const int wpix = w0 + lx;
    const int hbase = h0 + 2 * wv;

    const float* hn = hist + n * 3 * HW;
    const float* xn = x    + n * 3 * HW;

    // ---- mv loads (coalesced float2, issue first) ----
    const float2 g0 = ((const float2*)mv)[n * HW + hbase * W + wpix];
    const float2 g1 = ((const float2*)mv)[n * HW + (hbase + 1) * W + wpix];

    // ---- stage history window into LDS, f16 RGBA-interleaved ----
    const bool interior = (tx >= 1) && (tx <= NTX - 2) &&
                          (h0 >= 4) && (h0 + TH + 3 <= H - 1);
    if (interior) {
        for (int idx = threadIdx.x; idx < NTEX; idx += 256) {
            int r  = idx / HCOLS;
            int cc = idx - r * HCOLS;
            const float* src = hn + (h0 - 4 + r) * W + (w0 - 8) + cc;
            Lh[idx] = make_uint2(pk(src[0], src[HW]), pk(src[2 * HW], 0.0f));
        }
    } else {
        for (int idx = threadIdx.x; idx < NTEX; idx += 256) {
            int r  = idx / HCOLS;
            int cc = idx - r * HCOLS;
            int gr = iclamp(h0 - 4 + r, 0, H - 1);
            int gc = iclamp(w0 - 8 + cc, 0, W - 1);
            const float* src = hn + gr * W + gc;
            Lh[idx] = make_uint2(pk(src[0], src[HW]), pk(src[2 * HW], 0.0f));
        }
    }

    // ---- x neighborhood (coalesced VMEM; overlaps staging latency) ----
    int rg0 = iclamp(hbase - 1, 0, H - 1) * W;
    int rg1 = hbase * W;
    int rg2 = (hbase + 1) * W;
    int rg3 = iclamp(hbase + 2, 0, H - 1) * W;
    const int rg[4] = {rg0, rg1, rg2, rg3};

    float hmx[3][4], hmn[3][4], xmid[3][4];
    if (tx >= 1 && tx <= NTX - 2) {
#pragma unroll
        for (int c = 0; c < 3; ++c) {
            const float* xc = xn + c * HW + wpix;
#pragma unroll
            for (int rr = 0; rr < 4; ++rr) {
                const float* p = xc + rg[rr];
                float a = p[-1], b = p[0], e = p[1];
                hmx[c][rr]  = fmaxf(fmaxf(a, b), e);
                hmn[c][rr]  = fminf(fminf(a, b), e);
                xmid[c][rr] = b;
            }
        }
    } else {
        const int wm = max(wpix - 1, 0), wp = min(wpix + 1, W - 1);
#pragma unroll
        for (int c = 0; c < 3; ++c) {
            const float* xc = xn + c * HW;
#pragma unroll
            for (int rr = 0; rr < 4; ++rr) {
                float a = xc[rg[rr] + wm];
                float b = xc[rg[rr] + wpix];
                float e = xc[rg[rr] + wp];
                hmx[c][rr]  = fmaxf(fmaxf(a, b), e);
                hmn[c][rr]  = fminf(fminf(a, b), e);
                xmid[c][rr] = b;
            }
        }
    }

    // ---- bicubic setup for both pixels (overlaps staging latency) ----
    Setup sx0 = axis_setup(g0.x, (float)W);
    Setup sy0 = axis_setup(g0.y, (float)H);
    Setup sx1 = axis_setup(g1.x, (float)W);
    Setup sy1 = axis_setup(g1.y, (float)H);

    __syncthreads();

    float* on = out + n * 3 * HW;

#pragma unroll
    for (int p = 0; p < 2; ++p) {
        const Setup& sx = p ? sx1 : sx0;
        const Setup& sy = p ? sy1 : sy0;

        const int lrA = iclamp(sy.mA - (h0 - 4), 0, HROWS - 1);
        const int lr1 = iclamp(sy.m1 - (h0 - 4), 0, HROWS - 1);
        const int lr2 = iclamp(sy.m2 - (h0 - 4), 0, HROWS - 1);
        const int lrB = iclamp(sy.mB - (h0 - 4), 0, HROWS - 1);
        const int lcA = iclamp(sx.mA - (w0 - 8), 0, HCOLS - 1);
        const int lc1 = iclamp(sx.m1 - (w0 - 8), 0, HCOLS - 1);
        const int lc2 = iclamp(sx.m2 - (w0 - 8), 0, HCOLS - 1);
        const int lcB = iclamp(sx.mB - (w0 - 8), 0, HCOLS - 1);

        const int rA = lrA * HCOLS, r1 = lr1 * HCOLS, r2 = lr2 * HCOLS, rB = lrB * HCOLS;

        // 12 b64 tap reads — each carries all 3 channels (f16)
        uint2 tA1 = Lh[rA + lc1], tA2 = Lh[rA + lc2];        // s1 pair
        uint2 tB1 = Lh[rB + lc1], tB2 = Lh[rB + lc2];        // s4 pair
        uint2 tL1 = Lh[r1 + lcA], tL2 = Lh[r2 + lcA];        // s2 pair
        uint2 tR1 = Lh[r1 + lcB], tR2 = Lh[r2 + lcB];        // s3 pair
        uint2 tC11 = Lh[r1 + lc1], tC12 = Lh[r1 + lc2];      // s5 quad
        uint2 tC21 = Lh[r2 + lc1], tC22 = Lh[r2 + lc2];

        const float tx_ = sx.t, ty_ = sy.t;
        const float omtx = 1.0f - tx_, omty = 1.0f - ty_;
        const float ww1 = sx.w12 * sy.w0;
        const float ww2 = sx.w0  * sy.w12;
        const float ww3 = sx.w3  * sy.w12;
        const float ww4 = sx.w12 * sy.w3;
        const float ww5 = sx.w12 * sy.w12;
        const float rrec = __fdividef(1.0f, ww1 + ww2 + ww3 + ww4 + ww5);

        // broadcast weights to packed f16
        const h2 htx = bc2(tx_),  homtx = bc2(omtx);
        const h2 hty = bc2(ty_),  homty = bc2(omty);
        const h2 hw1 = bc2(ww1), hw2 = bc2(ww2), hw3 = bc2(ww3),
                 hw4 = bc2(ww4), hw5 = bc2(ww5);

        // packed-f16 combine: lane .x=(R,G), .y=(B,pad)
        h2 A1rg = toh2(tA1.x), A1bp = toh2(tA1.y), A2rg = toh2(tA2.x), A2bp = toh2(tA2.y);
        h2 B1rg = toh2(tB1.x), B1bp = toh2(tB1.y), B2rg = toh2(tB2.x), B2bp = toh2(tB2.y);
        h2 L1rg = toh2(tL1.x), L1bp = toh2(tL1.y), L2rg = toh2(tL2.x), L2bp = toh2(tL2.y);
        h2 R1rg = toh2(tR1.x), R1bp = toh2(tR1.y), R2rg = toh2(tR2.x), R2bp = toh2(tR2.y);
        h2 C11rg = toh2(tC11.x), C11bp = toh2(tC11.y), C12rg = toh2(tC12.x), C12bp = toh2(tC12.y);
        h2 C21rg = toh2(tC21.x), C21bp = toh2(tC21.y), C22rg = toh2(tC22.x), C22bp = toh2(tC22.y);

        h2 s1rg = A1rg * homtx + A2rg * htx,  s1bp = A1bp * homtx + A2bp * htx;
        h2 s4rg = B1rg * homtx + B2rg * htx,  s4bp = B1bp * homtx + B2bp * htx;
        h2 s2rg = L1rg * homty + L2rg * hty,  s2bp = L1bp * homty + L2bp * hty;
        h2 s3rg = R1rg * homty + R2rg * hty,  s3bp = R1bp * homty + R2bp * hty;
        h2 s5rg = (C11rg * homtx + C12rg * htx) * homty + (C21rg * homtx + C22rg * htx) * hty;
        h2 s5bp = (C11bp * homtx + C12bp * htx) * homty + (C21bp * homtx + C22bp * htx) * hty;

        h2 accrg = s1rg * hw1 + s2rg * hw2 + s3rg * hw3 + s4rg * hw4 + s5rg * hw5;
        h2 accbp = s1bp * hw1 + s2bp * hw2 + s3bp * hw3 + s4bp * hw4 + s5bp * hw5;

        float rv[3] = { (float)accrg[0] * rrec, (float)accrg[1] * rrec, (float)accbp[0] * rrec };

        const int gpix = (hbase + p) * W + wpix;
#pragma unroll
        for (int c = 0; c < 3; ++c) {
            float mxv = fmaxf(fmaxf(hmx[c][p], hmx[c][p + 1]), hmx[c][p + 2]);
            float mnv = fminf(fminf(hmn[c][p], hmn[c][p + 1]), hmn[c][p + 2]);
            float reproj = fminf(fmaxf(rv[c], mnv), mxv);
            on[c * HW + gpix] = ALPHA * xmid[c][p + 1] + (1.0f - ALPHA) * reproj;
        }
    }
}

extern "C" void kernel_launch(void* const* d_in, const int* in_sizes, int n_in,
                              void* d_out, int out_size, void* d_ws, size_t ws_size,
                              hipStream_t stream) {
    const float* x    = (const float*)d_in[0];
    const float* mv   = (const float*)d_in[1];
    const float* hist = (const float*)d_in[2];
    float* out = (float*)d_out;

    constexpr int NWG = 2 * (1920 / TW) * (1080 / TH);  // 8100
    taa_kernel<<<dim3(NWG, 1, 1), dim3(256, 1, 1), 0, stream>>>(x, mv, hist, out);
}